// Round 8
// baseline (412.341 us; speedup 1.0000x reference)
//
#include <hip/hip_runtime.h>
#include <stdint.h>

using f32x4   = __attribute__((ext_vector_type(4))) float;
using short8  = __attribute__((ext_vector_type(8))) short;
using float4v = __attribute__((ext_vector_type(4))) float;
using float2v = __attribute__((ext_vector_type(2))) float;
using uint2v  = __attribute__((ext_vector_type(2))) unsigned int;
using uint4v  = __attribute__((ext_vector_type(4))) unsigned int;

#define NCOL 11008
#define KDIM 4096
#define LSTRIDE 264   // LDS bytes per k-row: 128 cols * 2B + 8B pad (2-way reads)

__device__ __forceinline__ unsigned pk_bf16(float a, float b) {
  unsigned ua = __float_as_uint(a); ua += 0x7fffu + ((ua >> 16) & 1u);  // RNE
  unsigned ub = __float_as_uint(b); ub += 0x7fffu + ((ub >> 16) & 1u);
  return (ua >> 16) | (ub & 0xffff0000u);
}

// ---- kernel 1: mask (fp64-exact; decisions verified green in R5/R7) +
//      write mask-zeroed bf16 copy of x into ws. grid (8 rb, 8 kgrp), 256 thr.
__global__ __launch_bounds__(256) void mask_convert_kernel(
    const float* __restrict__ x, unsigned* __restrict__ xbf) {
  const int rb = blockIdx.x;
  const int g  = blockIdx.y;
  const int t  = threadIdx.x;
  __shared__ double part[256];
  __shared__ unsigned sh_bits;

  const float* base = x + (size_t)rb * 16 * KDIM + g * 512 + t * 2;
  double s = 0.0;
#pragma unroll
  for (int r = 0; r < 16; ++r) {
    float2v a = *(const float2v*)(base + (size_t)r * KDIM);
    s += (double)fabsf(a[0]) + (double)fabsf(a[1]);
  }
  part[t] = s;
  __syncthreads();
  if (t < 8) {                        // t = kb-local (8 kbs per 512-col group)
    double acc = 0.0;
#pragma unroll
    for (int u = 0; u < 32; ++u) acc += part[t * 32 + u];
    bool on = (acc * (1.0 / 1024.0)) > (double)0.8f;
    unsigned long long bal = __ballot(on);
    if (t == 0) sh_bits = (unsigned)(bal & 0xffu);
  }
  __syncthreads();
  const unsigned keep = (sh_bits >> (t >> 5)) & 1u;

  unsigned* dst = xbf + (size_t)rb * 16 * (KDIM / 2) + g * 256 + t;
#pragma unroll
  for (int r = 0; r < 16; ++r) {      // reload (L1-hot) + pack/zero + store
    float2v a = *(const float2v*)(base + (size_t)r * KDIM);
    dst[(size_t)r * (KDIM / 2)] = keep ? pk_bf16(a[0], a[1]) : 0u;
  }
}

// ---- kernel 2: dense GEMM on masked bf16 x. grid (8 rb, 86 n0), 256 thr.
// M=16, N=128 per block; dense k-loop 0..63 keeps all blocks in lockstep ->
// DRAM page locality + L3 dedup of the 8 rb-duplicates. No atomics.
// Wave wv owns cols [wv*32,+32) as even/odd column fragments.
__global__ __launch_bounds__(256) void gemm_kernel(
    const unsigned* __restrict__ xbf, const float* __restrict__ w,
    const float* __restrict__ bias, float* __restrict__ out) {

  __shared__ __align__(16) uint8_t lds[64 * LSTRIDE];

  const int tid  = threadIdx.x;
  const int lane = tid & 63;
  const int wv   = tid >> 6;
  const int c    = lane & 15;
  const int q    = lane >> 4;
  const int rb   = blockIdx.x;
  const int n0   = blockIdx.y * 128;

  f32x4 acc[2] = {};                  // even / odd column fragments

  // W staging: thread t -> k = r*8 + (t>>5), n = (t&31)*4  (float4 load)
  const int sk = tid >> 5;
  const int sn = (tid & 31) * 4;
  uint8_t* wS = lds + (size_t)sk * LSTRIDE + sn * 2;

  // A source (bf16, L2-resident): uint4v idx = (rb*16+c)*512 + kb*8 + ks*4 + q
  const uint4v* aBase = (const uint4v*)xbf + (size_t)(rb * 16 + c) * (KDIM / 8) + q;

  float4v wr[8];
#define ISSUE_W(KB)                                                      \
  {                                                                      \
    const float* wp = w + (size_t)((KB)*64 + sk) * NCOL + n0 + sn;       \
    _Pragma("unroll")                                                    \
    for (int r = 0; r < 8; ++r)                                          \
      wr[r] = *(const float4v*)(wp + (size_t)r * 8 * NCOL);              \
  }

  ISSUE_W(0);
  for (int kb = 0; kb < 64; ++kb) {
    __syncthreads();                  // prior compute done with LDS
#pragma unroll
    for (int r = 0; r < 8; ++r) {     // vmcnt wait on wr lands here
      uint2v v;
      v[0] = pk_bf16(wr[r][0], wr[r][1]);
      v[1] = pk_bf16(wr[r][2], wr[r][3]);
      *(uint2v*)(wS + (size_t)r * 8 * LSTRIDE) = v;
    }
    __syncthreads();
    if (kb < 63) ISSUE_W(kb + 1);     // prefetch overlaps compute

#pragma unroll
    for (int ks = 0; ks < 2; ++ks) {
      union { uint4v u; short8 v; } am;
      am.u = aBase[kb * 8 + ks * 4];  // 16B bf16 A-fragment, no repack

      // B fragments: dword j = cols (2c,2c+1) at k = ks*32 + q*8 + j
      const uint8_t* wb = lds + (size_t)(ks * 32 + q * 8) * LSTRIDE + (wv * 32 + 2 * c) * 2;
      unsigned wj[8];
#pragma unroll
      for (int j = 0; j < 8; ++j)
        wj[j] = *(const unsigned*)(wb + (size_t)j * LSTRIDE);
      union { short8 v; unsigned u[4]; } be, bo;
#pragma unroll
      for (int p = 0; p < 4; ++p) {
        be.u[p] = (wj[2 * p] & 0x0000ffffu) | (wj[2 * p + 1] << 16);   // even col
        bo.u[p] = (wj[2 * p] >> 16) | (wj[2 * p + 1] & 0xffff0000u);   // odd col
      }
      acc[0] = __builtin_amdgcn_mfma_f32_16x16x32_bf16(am.v, be.v, acc[0], 0, 0, 0);
      acc[1] = __builtin_amdgcn_mfma_f32_16x16x32_bf16(am.v, bo.v, acc[1], 0, 0, 0);
    }
  }
#undef ISSUE_W

  // epilogue: D row = q*4+p, cols (2c,2c+1); direct fp32 store + bias
  const int colE = n0 + wv * 32 + 2 * c;
  const float bE = bias[colE];
  const float bO = bias[colE + 1];
#pragma unroll
  for (int p = 0; p < 4; ++p) {
    const int row = rb * 16 + q * 4 + p;
    float2v st;
    st[0] = acc[0][p] + bE;
    st[1] = acc[1][p] + bO;
    *(float2v*)(out + (size_t)row * NCOL + colE) = st;   // 8B-aligned
  }
}

extern "C" void kernel_launch(void* const* d_in, const int* in_sizes, int n_in,
                              void* d_out, int out_size, void* d_ws, size_t ws_size,
                              hipStream_t stream) {
  const float* x    = (const float*)d_in[0];
  const float* w    = (const float*)d_in[1];
  const float* bias = (const float*)d_in[2];
  float* out        = (float*)d_out;
  unsigned* xbf     = (unsigned*)d_ws;    // 128 x 4096 bf16 (1 MiB)

  hipLaunchKernelGGL(mask_convert_kernel, dim3(8, 8), dim3(256), 0, stream, x, xbf);
  hipLaunchKernelGGL(gemm_kernel, dim3(8, 86), dim3(256), 0, stream,
                     xbf, w, bias, out);
}

// Round 9
// 287.680 us; speedup vs baseline: 1.4333x; 1.4333x over previous
//
#include <hip/hip_runtime.h>
#include <stdint.h>

using f32x4   = __attribute__((ext_vector_type(4))) float;
using short8  = __attribute__((ext_vector_type(8))) short;
using float4v = __attribute__((ext_vector_type(4))) float;
using float2v = __attribute__((ext_vector_type(2))) float;
using uint2v  = __attribute__((ext_vector_type(2))) unsigned int;
using uint4v  = __attribute__((ext_vector_type(4))) unsigned int;

#define NCOL 11008
#define KDIM 4096
#define BSTRIDE 72    // LDS bytes per k-row: 32 cols * 2B + 8B pad

__device__ __forceinline__ unsigned pk_bf16(float a, float b) {
  unsigned ua = __float_as_uint(a); ua += 0x7fffu + ((ua >> 16) & 1u);  // RNE
  unsigned ub = __float_as_uint(b); ub += 0x7fffu + ((ub >> 16) & 1u);
  return (ua >> 16) | (ub & 0xffff0000u);
}

// ---- kernel 1: mask (fp64-exact; verified green R5/R7/R8) + write
//      mask-zeroed bf16 copy of x into ws. grid (8 rb, 8 kgrp), 256 thr.
__global__ __launch_bounds__(256) void mask_convert_kernel(
    const float* __restrict__ x, unsigned* __restrict__ xbf) {
  const int rb = blockIdx.x;
  const int g  = blockIdx.y;
  const int t  = threadIdx.x;
  __shared__ double part[256];
  __shared__ unsigned sh_bits;

  const float* base = x + (size_t)rb * 16 * KDIM + g * 512 + t * 2;
  double s = 0.0;
#pragma unroll
  for (int r = 0; r < 16; ++r) {
    float2v a = *(const float2v*)(base + (size_t)r * KDIM);
    s += (double)fabsf(a[0]) + (double)fabsf(a[1]);
  }
  part[t] = s;
  __syncthreads();
  if (t < 8) {                        // t = kb-local (8 kbs per 512-col group)
    double acc = 0.0;
#pragma unroll
    for (int u = 0; u < 32; ++u) acc += part[t * 32 + u];
    bool on = (acc * (1.0 / 1024.0)) > (double)0.8f;
    unsigned long long bal = __ballot(on);
    if (t == 0) sh_bits = (unsigned)(bal & 0xffu);
  }
  __syncthreads();
  const unsigned keep = (sh_bits >> (t >> 5)) & 1u;

  unsigned* dst = xbf + (size_t)rb * 16 * (KDIM / 2) + g * 256 + t;
#pragma unroll
  for (int r = 0; r < 16; ++r) {      // reload (L1-hot) + pack/zero + store
    float2v a = *(const float2v*)(base + (size_t)r * KDIM);
    dst[(size_t)r * (KDIM / 2)] = keep ? pk_bf16(a[0], a[1]) : 0u;
  }
}

// ---- kernel 2: dense GEMM on masked bf16 x. grid 344, 256 thr (4 waves).
// M=128 x N=32 per block, full K: every W byte requested by EXACTLY ONE
// block chip-wide (no rb-duplication -> no L3 thrash), direct stores (no
// atomics). LDS double-buffered W tile, one barrier per kb.
// Wave wv owns m-bands {wv*2, wv*2+1}; cols as even/odd fragments.
__global__ __launch_bounds__(256) void gemm_kernel(
    const unsigned* __restrict__ xbf, const float* __restrict__ w,
    const float* __restrict__ bias, float* __restrict__ out) {

  __shared__ __align__(16) uint8_t lds[2 * 64 * BSTRIDE];

  const int tid  = threadIdx.x;
  const int lane = tid & 63;
  const int wv   = tid >> 6;
  const int c    = lane & 15;
  const int q    = lane >> 4;
  const int n0   = blockIdx.x * 32;

  f32x4 acc[2][2] = {};               // [band][even/odd]

  // W staging: thread t -> rows {t>>3, (t>>3)+32}, col chunk (t&7)*4
  const int sk = tid >> 3;            // 0..31
  const int sn = (tid & 7) * 4;       // 0,4,..,28
  const size_t wOff = (size_t)sk * NCOL + n0 + sn;

  float4v wr0, wr1;
#define ISSUE_W(KB)                                                       \
  {                                                                       \
    const float* wp = w + (size_t)(KB) * 64 * NCOL + wOff;                \
    wr0 = *(const float4v*)(wp);                                          \
    wr1 = *(const float4v*)(wp + (size_t)32 * NCOL);                      \
  }

  // A source (bf16 masked x, L2-resident): uint4v idx = row*512 + kb*8 + ks*4 + q
  const uint4v* aB0 = (const uint4v*)xbf + (size_t)((wv * 2 + 0) * 16 + c) * (KDIM / 8) + q;
  const uint4v* aB1 = (const uint4v*)xbf + (size_t)((wv * 2 + 1) * 16 + c) * (KDIM / 8) + q;

  ISSUE_W(0);
  int p = 0;
  for (int kb = 0; kb < 64; ++kb) {
    uint8_t* buf = lds + p * 64 * BSTRIDE;
    // store current kb's W regs (vmcnt waits land here), bf16-packed
    {
      uint2v v;
      v[0] = pk_bf16(wr0[0], wr0[1]);
      v[1] = pk_bf16(wr0[2], wr0[3]);
      *(uint2v*)(buf + (size_t)sk * BSTRIDE + sn * 2) = v;
      uint2v u;
      u[0] = pk_bf16(wr1[0], wr1[1]);
      u[1] = pk_bf16(wr1[2], wr1[3]);
      *(uint2v*)(buf + (size_t)(sk + 32) * BSTRIDE + sn * 2) = u;
    }
    if (kb < 63) ISSUE_W(kb + 1);     // prefetch next kb (overlaps compute)
    __syncthreads();                  // single barrier per kb (dbuf)

#pragma unroll
    for (int ks = 0; ks < 2; ++ks) {
      union { uint4v u; short8 v; } a0, a1;
      a0.u = aB0[kb * 8 + ks * 4];
      a1.u = aB1[kb * 8 + ks * 4];

      // B fragments: dword j = cols (2c,2c+1) at k = ks*32 + q*8 + j
      const uint8_t* wb = buf + (size_t)(ks * 32 + q * 8) * BSTRIDE + c * 4;
      unsigned wj[8];
#pragma unroll
      for (int j = 0; j < 8; ++j)
        wj[j] = *(const unsigned*)(wb + (size_t)j * BSTRIDE);
      union { short8 v; unsigned u[4]; } be, bo;
#pragma unroll
      for (int pp = 0; pp < 4; ++pp) {
        be.u[pp] = (wj[2 * pp] & 0x0000ffffu) | (wj[2 * pp + 1] << 16);   // even
        bo.u[pp] = (wj[2 * pp] >> 16) | (wj[2 * pp + 1] & 0xffff0000u);   // odd
      }
      acc[0][0] = __builtin_amdgcn_mfma_f32_16x16x32_bf16(a0.v, be.v, acc[0][0], 0, 0, 0);
      acc[0][1] = __builtin_amdgcn_mfma_f32_16x16x32_bf16(a0.v, bo.v, acc[0][1], 0, 0, 0);
      acc[1][0] = __builtin_amdgcn_mfma_f32_16x16x32_bf16(a1.v, be.v, acc[1][0], 0, 0, 0);
      acc[1][1] = __builtin_amdgcn_mfma_f32_16x16x32_bf16(a1.v, bo.v, acc[1][1], 0, 0, 0);
    }
    p ^= 1;
  }
#undef ISSUE_W

  // epilogue: D row = band*16 + q*4 + pp, cols (2c,2c+1); direct fp32 store
  const int colE = n0 + 2 * c;
  const float bE = bias[colE];
  const float bO = bias[colE + 1];
#pragma unroll
  for (int b = 0; b < 2; ++b) {
#pragma unroll
    for (int pp = 0; pp < 4; ++pp) {
      const int row = (wv * 2 + b) * 16 + q * 4 + pp;
      float2v st;
      st[0] = acc[b][0][pp] + bE;
      st[1] = acc[b][1][pp] + bO;
      *(float2v*)(out + (size_t)row * NCOL + colE) = st;   // 8B-aligned
    }
  }
}

extern "C" void kernel_launch(void* const* d_in, const int* in_sizes, int n_in,
                              void* d_out, int out_size, void* d_ws, size_t ws_size,
                              hipStream_t stream) {
  const float* x    = (const float*)d_in[0];
  const float* w    = (const float*)d_in[1];
  const float* bias = (const float*)d_in[2];
  float* out        = (float*)d_out;
  unsigned* xbf     = (unsigned*)d_ws;    // 128 x 4096 bf16 (1 MiB)

  hipLaunchKernelGGL(mask_convert_kernel, dim3(8, 8), dim3(256), 0, stream, x, xbf);
  hipLaunchKernelGGL(gemm_kernel, dim3(344), dim3(256), 0, stream,
                     xbf, w, bias, out);
}